// Round 4
// baseline (177.376 us; speedup 1.0000x reference)
//
#include <hip/hip_runtime.h>
#include <math.h>

// HadamardProj: out[b,o] = -scale * (x[b]/(||x[b]||+eps)) . H[o,:] + bias[o]
// H[o,i] = (-1)^popcount(o&i), i<2048  =>  H row o == H row (o mod 2048)
// => y[b] = FWHT_2048(x[b]) (Sylvester), out[b,o] = -scale*inv_norm*y[o&2047] + bias[o]
//
// Register-resident variant: lane owns e = j*256 + lane*4 + c (j=0..7, c=0..3).
//   FWHT = 2 stages in-float4 (h=1,2) + 6 shuffle stages (h=4..128) + 3 reg stages (h=256..1024).
//   Output window w element o = w*2048 + j*256 + lane*4 is lane-local -> NO LDS, no barrier,
//   fully coalesced dwordx4 loads/stores everywhere.

typedef float f32x4 __attribute__((ext_vector_type(4)));

constexpr int N_IN  = 2048;    // 2^11
constexpr int N_OUT = 10000;
constexpr int ROWS_PER_BLOCK = 4;  // one wave64 per row

__global__ __launch_bounds__(256, 4) void fwht_proj_kernel(
    const float* __restrict__ x,
    const float* __restrict__ scale,
    const float* __restrict__ bias,
    float* __restrict__ out)
{
    const int wave = threadIdx.x >> 6;
    const int lane = threadIdx.x & 63;
    const int row  = (blockIdx.x << 2) + wave;     // rows % 4 == 0

    const float* __restrict__ xrow = x + (size_t)row * N_IN;

    // Vector loads: lane reads f32x4 at j*256 + lane*4  (1 KiB/instr, coalesced)
    f32x4 v[8];
    float ss = 0.0f;
#pragma unroll
    for (int j = 0; j < 8; ++j) {
        v[j] = *reinterpret_cast<const f32x4*>(xrow + (j << 8) + (lane << 2));
        ss = fmaf(v[j].x, v[j].x, ss);
        ss = fmaf(v[j].y, v[j].y, ss);
        ss = fmaf(v[j].z, v[j].z, ss);
        ss = fmaf(v[j].w, v[j].w, ss);
    }
#pragma unroll
    for (int m = 1; m < 64; m <<= 1)
        ss += __shfl_xor(ss, m, 64);
    const float inv = 1.0f / (sqrtf(ss) + 1e-8f);  // matches x/(norm+eps)

    // Stages h=1, h=2: inside each float4
#pragma unroll
    for (int j = 0; j < 8; ++j) {
        const f32x4 a = v[j];
        f32x4 t;
        t.x = a.x + a.y;  t.y = a.x - a.y;
        t.z = a.z + a.w;  t.w = a.z - a.w;
        f32x4 u;
        u.x = t.x + t.z;  u.y = t.y + t.w;
        u.z = t.x - t.z;  u.w = t.y - t.w;
        v[j] = u;
    }
    // Stages h=4..128: cross-lane, lane xor mask m = h/4 = 1..32
#pragma unroll
    for (int m = 1; m <= 32; m <<= 1) {
        const bool lo = (lane & m) == 0;
#pragma unroll
        for (int j = 0; j < 8; ++j) {
            f32x4 o;
            o.x = __shfl_xor(v[j].x, m, 64);
            o.y = __shfl_xor(v[j].y, m, 64);
            o.z = __shfl_xor(v[j].z, m, 64);
            o.w = __shfl_xor(v[j].w, m, 64);
            v[j] = lo ? (v[j] + o) : (o - v[j]);
        }
    }
    // Stages h=256,512,1024: register index xor 1,2,4
#pragma unroll
    for (int jm = 1; jm <= 4; jm <<= 1) {
#pragma unroll
        for (int j = 0; j < 8; ++j) {
            if ((j & jm) == 0) {
                const f32x4 a = v[j], b = v[j ^ jm];
                v[j]      = a + b;
                v[j ^ jm] = a - b;
            }
        }
    }

    const float s = -scale[0] * inv;   // fold norm + negated scale into one FMA coeff
    float* __restrict__ orow = out + (size_t)row * N_OUT;

    // Register-resident epilogue: out[w*2048 + j*256 + lane*4 + c] = s*v[j][c] + bias[...]
#pragma unroll
    for (int w = 0; w < 4; ++w) {
#pragma unroll 4
        for (int j = 0; j < 8; ++j) {
            const int o = (w << 11) + (j << 8) + (lane << 2);
            const f32x4 b = *reinterpret_cast<const f32x4*>(bias + o);
            f32x4 r;
            r.x = fmaf(s, v[j].x, b.x);
            r.y = fmaf(s, v[j].y, b.y);
            r.z = fmaf(s, v[j].z, b.z);
            r.w = fmaf(s, v[j].w, b.w);
            *reinterpret_cast<f32x4*>(orow + o) = r;
        }
    }
    // Partial window w=4: 8192..9999. j=0..6 full (max o = 8192+1536+252 = 9980+3 ok),
    // j=7 only lanes 0..3 (o = 9984..9996).
#pragma unroll 4
    for (int j = 0; j < 7; ++j) {
        const int o = 8192 + (j << 8) + (lane << 2);
        const f32x4 b = *reinterpret_cast<const f32x4*>(bias + o);
        f32x4 r;
        r.x = fmaf(s, v[j].x, b.x);
        r.y = fmaf(s, v[j].y, b.y);
        r.z = fmaf(s, v[j].z, b.z);
        r.w = fmaf(s, v[j].w, b.w);
        *reinterpret_cast<f32x4*>(orow + o) = r;
    }
    if (lane < 4) {
        const int o = 9984 + (lane << 2);
        const f32x4 b = *reinterpret_cast<const f32x4*>(bias + o);
        f32x4 r;
        r.x = fmaf(s, v[7].x, b.x);
        r.y = fmaf(s, v[7].y, b.y);
        r.z = fmaf(s, v[7].z, b.z);
        r.w = fmaf(s, v[7].w, b.w);
        *reinterpret_cast<f32x4*>(orow + o) = r;
    }
}

extern "C" void kernel_launch(void* const* d_in, const int* in_sizes, int n_in,
                              void* d_out, int out_size, void* d_ws, size_t ws_size,
                              hipStream_t stream) {
    const float* x     = (const float*)d_in[0];
    // d_in[1] = proj: unused — Hadamard structure computed via FWHT
    const float* scale = (const float*)d_in[2];
    const float* bias  = (const float*)d_in[3];
    float* out = (float*)d_out;

    const int rows = in_sizes[0] / N_IN;            // 16384
    dim3 grid(rows / ROWS_PER_BLOCK), block(256);
    hipLaunchKernelGGL(fwht_proj_kernel, grid, block, 0, stream,
                       x, scale, bias, out);
}

// Round 5
// 164.728 us; speedup vs baseline: 1.0768x; 1.0768x over previous
//
#include <hip/hip_runtime.h>
#include <math.h>

// HadamardProj: out[b,o] = -scale * (x[b]/(||x[b]||+eps)) . H[o,:] + bias[o]
// H[o,i] = (-1)^popcount(o&i), i<2048  =>  H row o == H row (o mod 2048)
// => y[b] = FWHT_2048(x[b]) (Sylvester), out[b,o] = -scale*inv_norm*y[o&2047] + bias[o]
//
// Register-resident FWHT (lane owns e = j*256 + lane*4 + c), NO staging LDS.
// bias (40 KB) is staged in LDS once per block: the 655 MB out-write stream
// evicts bias from L2, so per-row global bias reads leak ~300 MB to HBM.

typedef float f32x4 __attribute__((ext_vector_type(4)));

constexpr int N_IN  = 2048;    // 2^11
constexpr int N_OUT = 10000;
constexpr int ROWS_PER_BLOCK = 4;  // one wave64 per row

__global__ __launch_bounds__(256, 4) void fwht_proj_kernel(
    const float* __restrict__ x,
    const float* __restrict__ scale,
    const float* __restrict__ bias,
    float* __restrict__ out)
{
    __shared__ f32x4 biaslds[N_OUT / 4];   // 2500 f32x4 = 40,000 B

    // Cooperative bias staging: 2500 vec4 loads across 256 threads (coalesced).
    {
        const f32x4* __restrict__ b4 = reinterpret_cast<const f32x4*>(bias);
        for (int i = threadIdx.x; i < N_OUT / 4; i += 256)
            biaslds[i] = b4[i];
    }
    __syncthreads();   // one barrier; epilogue reads biaslds

    const int wave = threadIdx.x >> 6;
    const int lane = threadIdx.x & 63;
    const int row  = (blockIdx.x << 2) + wave;     // rows % 4 == 0

    const float* __restrict__ xrow = x + (size_t)row * N_IN;

    // Vector loads: lane reads f32x4 at j*256 + lane*4  (1 KiB/instr, coalesced)
    f32x4 v[8];
    float ss = 0.0f;
#pragma unroll
    for (int j = 0; j < 8; ++j) {
        v[j] = *reinterpret_cast<const f32x4*>(xrow + (j << 8) + (lane << 2));
        ss = fmaf(v[j].x, v[j].x, ss);
        ss = fmaf(v[j].y, v[j].y, ss);
        ss = fmaf(v[j].z, v[j].z, ss);
        ss = fmaf(v[j].w, v[j].w, ss);
    }
#pragma unroll
    for (int m = 1; m < 64; m <<= 1)
        ss += __shfl_xor(ss, m, 64);
    const float inv = 1.0f / (sqrtf(ss) + 1e-8f);  // matches x/(norm+eps)

    // Stages h=1, h=2: inside each float4
#pragma unroll
    for (int j = 0; j < 8; ++j) {
        const f32x4 a = v[j];
        f32x4 t;
        t.x = a.x + a.y;  t.y = a.x - a.y;
        t.z = a.z + a.w;  t.w = a.z - a.w;
        f32x4 u;
        u.x = t.x + t.z;  u.y = t.y + t.w;
        u.z = t.x - t.z;  u.w = t.y - t.w;
        v[j] = u;
    }
    // Stages h=4..128: cross-lane, lane xor mask m = h/4 = 1..32
#pragma unroll
    for (int m = 1; m <= 32; m <<= 1) {
        const bool lo = (lane & m) == 0;
#pragma unroll
        for (int j = 0; j < 8; ++j) {
            f32x4 o;
            o.x = __shfl_xor(v[j].x, m, 64);
            o.y = __shfl_xor(v[j].y, m, 64);
            o.z = __shfl_xor(v[j].z, m, 64);
            o.w = __shfl_xor(v[j].w, m, 64);
            v[j] = lo ? (v[j] + o) : (o - v[j]);
        }
    }
    // Stages h=256,512,1024: register index xor 1,2,4
#pragma unroll
    for (int jm = 1; jm <= 4; jm <<= 1) {
#pragma unroll
        for (int j = 0; j < 8; ++j) {
            if ((j & jm) == 0) {
                const f32x4 a = v[j], b = v[j ^ jm];
                v[j]      = a + b;
                v[j ^ jm] = a - b;
            }
        }
    }

    const float s = -scale[0] * inv;   // fold norm + negated scale into one FMA coeff
    float* __restrict__ orow = out + (size_t)row * N_OUT;

    // Register-resident epilogue; bias from LDS (b128, conflict-free floor).
    // out[w*2048 + j*256 + lane*4 + c] = s*v[j][c] + bias[same]
#pragma unroll
    for (int w = 0; w < 4; ++w) {
#pragma unroll 4
        for (int j = 0; j < 8; ++j) {
            const int o = (w << 11) + (j << 8) + (lane << 2);
            const f32x4 b = biaslds[(w << 9) + (j << 6) + lane];
            f32x4 r;
            r.x = fmaf(s, v[j].x, b.x);
            r.y = fmaf(s, v[j].y, b.y);
            r.z = fmaf(s, v[j].z, b.z);
            r.w = fmaf(s, v[j].w, b.w);
            *reinterpret_cast<f32x4*>(orow + o) = r;
        }
    }
    // Partial window w=4: 8192..9999. j=0..6 full; j=7 only lanes 0..3.
#pragma unroll 4
    for (int j = 0; j < 7; ++j) {
        const int o = 8192 + (j << 8) + (lane << 2);
        const f32x4 b = biaslds[2048 + (j << 6) + lane];
        f32x4 r;
        r.x = fmaf(s, v[j].x, b.x);
        r.y = fmaf(s, v[j].y, b.y);
        r.z = fmaf(s, v[j].z, b.z);
        r.w = fmaf(s, v[j].w, b.w);
        *reinterpret_cast<f32x4*>(orow + o) = r;
    }
    if (lane < 4) {
        const int o = 9984 + (lane << 2);
        const f32x4 b = biaslds[2496 + lane];
        f32x4 r;
        r.x = fmaf(s, v[7].x, b.x);
        r.y = fmaf(s, v[7].y, b.y);
        r.z = fmaf(s, v[7].z, b.z);
        r.w = fmaf(s, v[7].w, b.w);
        *reinterpret_cast<f32x4*>(orow + o) = r;
    }
}

extern "C" void kernel_launch(void* const* d_in, const int* in_sizes, int n_in,
                              void* d_out, int out_size, void* d_ws, size_t ws_size,
                              hipStream_t stream) {
    const float* x     = (const float*)d_in[0];
    // d_in[1] = proj: unused — Hadamard structure computed via FWHT
    const float* scale = (const float*)d_in[2];
    const float* bias  = (const float*)d_in[3];
    float* out = (float*)d_out;

    const int rows = in_sizes[0] / N_IN;            // 16384
    dim3 grid(rows / ROWS_PER_BLOCK), block(256);
    hipLaunchKernelGGL(fwht_proj_kernel, grid, block, 0, stream,
                       x, scale, bias, out);
}